// Round 1
// baseline (1045.474 us; speedup 1.0000x reference)
//
#include <hip/hip_runtime.h>

// SubregionFeatureExtractor: per-batch, per-time, per-region channel means.
// features [B,T,C,D,H,W] f32, segmentation [B,1,D,H,W] int32 in 0..32.
// out [B,T,32,C] f32: mean over voxels with seg==r (r=1..32); empty -> 0.
//
// R4: drop the LDS transpose + sequential RMW entirely. Keep the dense
// global loads (4 lanes cover one 64B line per channel, 16 channels/instr),
// but accumulate with fire-and-forget ds_add_f32 (LDS float atomics) into a
// single block-shared acc[33][65]. No read-back dependency, 1 LDS op per
// element (was 4), no wave barriers, LDS/block 50.9KB -> 8.6KB (occupancy
// 12 -> ~24 waves/CU). Stride 65 => bank (r+cq)%32: ~2 lanes/bank (free).

#define BB 2
#define TT 8
#define CC 64
#define NVOX 110592      // 48*48*48
#define NREG 32
#define RS 33            // region slots incl. background 0
#define PAD 65           // acc row stride (floats); odd -> banks spread by region
#define WACC (RS * PAD)  // 2145 floats = 8580 B per block
#define VPW 256          // voxels per wave
#define CHUNKV 1024      // voxels per block (4 waves)

// ---------------- kernel 1: per-batch region histogram -------------------
__global__ __launch_bounds__(256) void seg_hist(const int* __restrict__ seg,
                                                float* __restrict__ counts) {
    __shared__ float h[4 * RS];
    const int tid = threadIdx.x;
    const int w = tid >> 6;
    for (int i = tid; i < 4 * RS; i += 256) h[i] = 0.f;
    __syncthreads();

    const int base = blockIdx.x * 1024 + tid * 4;  // flattened over B*NVOX
    const int b = base / NVOX;                      // block fully inside one batch
    const int4 s4 = *(const int4*)(seg + base);
    atomicAdd(&h[w * RS + s4.x], 1.f);
    atomicAdd(&h[w * RS + s4.y], 1.f);
    atomicAdd(&h[w * RS + s4.z], 1.f);
    atomicAdd(&h[w * RS + s4.w], 1.f);
    __syncthreads();

    if (tid < RS) {
        const float v = h[tid] + h[RS + tid] + h[2 * RS + tid] + h[3 * RS + tid];
        atomicAdd(&counts[b * RS + tid], v);
    }
}

// ---------------- kernel 2: streaming region sums ------------------------
// grid (NVOX/CHUNKV, T, B) = (108, 8, 2), block 256 (4 waves).
// Dense loads: lanes 0..3 cover one 64B line of one channel stream; each
// lane also loads the seg int4 for its own 4 voxels (static indexing).
// Accumulate with ds_add_f32 into one shared acc -- no RMW chain, no tile.
__global__ __launch_bounds__(256) void seg_sum(const float* __restrict__ feat,
                                               const int* __restrict__ seg,
                                               float* __restrict__ out) {
    __shared__ float acc[WACC];   // 8580 B
    const int tid = threadIdx.x;
    const int l = tid & 63;
    const int b = blockIdx.z;
    const int t = blockIdx.y;

    for (int i = tid; i < WACC; i += 256) acc[i] = 0.f;
    __syncthreads();

    const int v0 = blockIdx.x * CHUNKV + (tid >> 6) * VPW;
    const int cq = l >> 2;   // 0..15: channel within 16-group
    const int iq = l & 3;    // 0..3: float4 slot (voxels 4*iq..4*iq+3)
    const float* __restrict__ fp0 = feat + (size_t)(b * TT + t) * CC * NVOX
                                    + (size_t)cq * NVOX + v0 + iq * 4;
    const float* __restrict__ fp1 = fp0 + (size_t)16 * NVOX;
    const float* __restrict__ fp2 = fp0 + (size_t)32 * NVOX;
    const float* __restrict__ fp3 = fp0 + (size_t)48 * NVOX;
    const int* __restrict__ sb = seg + (size_t)b * NVOX + v0 + iq * 4;

    #pragma unroll 2
    for (int tj = 0; tj < 16; ++tj) {
        const int vo = tj * 16;
        const float4 f0 = *(const float4*)(fp0 + vo);
        const float4 f1 = *(const float4*)(fp1 + vo);
        const float4 f2 = *(const float4*)(fp2 + vo);
        const float4 f3 = *(const float4*)(fp3 + vo);
        const int4 s4 = *(const int4*)(sb + vo);   // regions of THIS lane's 4 voxels

        float* const a0 = acc + s4.x * PAD + cq;
        float* const a1 = acc + s4.y * PAD + cq;
        float* const a2 = acc + s4.z * PAD + cq;
        float* const a3 = acc + s4.w * PAD + cq;
        // voxel j gets channels {cq, cq+16, cq+32, cq+48}; +16/32/48 floats
        // fold into ds offset immediates (64/128/192 B).
        atomicAdd(a0,      f0.x); atomicAdd(a0 + 16, f1.x);
        atomicAdd(a0 + 32, f2.x); atomicAdd(a0 + 48, f3.x);
        atomicAdd(a1,      f0.y); atomicAdd(a1 + 16, f1.y);
        atomicAdd(a1 + 32, f2.y); atomicAdd(a1 + 48, f3.y);
        atomicAdd(a2,      f0.z); atomicAdd(a2 + 16, f1.z);
        atomicAdd(a2 + 32, f2.z); atomicAdd(a2 + 48, f3.z);
        atomicAdd(a3,      f0.w); atomicAdd(a3 + 16, f1.w);
        atomicAdd(a3 + 32, f2.w); atomicAdd(a3 + 48, f3.w);
    }
    __syncthreads();

    // single acc copy -> global atomics (skip background region 0)
    float* __restrict__ outbt = out + (size_t)(b * TT + t) * NREG * CC;
    for (int i = tid; i < NREG * CC; i += 256) {
        atomicAdd(&outbt[i], acc[((i >> 6) + 1) * PAD + (i & 63)]);
    }
}

// ---------------- kernel 3: divide by counts -----------------------------
__global__ __launch_bounds__(256) void seg_div(float* __restrict__ out,
                                               const float* __restrict__ counts) {
    const int i = blockIdx.x * 256 + threadIdx.x;       // out_size = 32768
    const int b = i >> 14;                              // / (TT*NREG*CC)
    const int r = ((i >> 6) & 31) + 1;                  // region 1..32
    const float cnt = counts[b * RS + r];
    const float v = out[i];
    out[i] = cnt > 0.f ? v / cnt : 0.f;
}

extern "C" void kernel_launch(void* const* d_in, const int* in_sizes, int n_in,
                              void* d_out, int out_size, void* d_ws, size_t ws_size,
                              hipStream_t stream) {
    const float* feat = (const float*)d_in[0];
    const int* seg = (const int*)d_in[1];
    float* out = (float*)d_out;
    float* counts = (float*)d_ws;  // BB*RS floats

    hipMemsetAsync(d_out, 0, (size_t)out_size * sizeof(float), stream);
    hipMemsetAsync(d_ws, 0, (size_t)(BB * RS) * sizeof(float), stream);

    seg_hist<<<dim3((BB * NVOX) / 1024), 256, 0, stream>>>(seg, counts);
    seg_sum<<<dim3(NVOX / CHUNKV, TT, BB), 256, 0, stream>>>(feat, seg, out);
    seg_div<<<dim3(out_size / 256), 256, 0, stream>>>(out, counts);
}

// Round 2
// 658.277 us; speedup vs baseline: 1.5882x; 1.5882x over previous
//
#include <hip/hip_runtime.h>

// SubregionFeatureExtractor: per-batch, per-time, per-region channel means.
// features [B,T,C,D,H,W] f32, segmentation [B,1,D,H,W] int32 in 0..32.
// out [B,T,32,C] f32: mean over voxels with seg==r (r=1..32); empty -> 0.
//
// R5: the segment-sum IS a one-hot GEMM: D[ch][reg] = sum_v feat[ch][v] *
// onehot[v][reg]. Use mfma_f32_16x16x32_bf16 with the one-hot B built in
// registers from seg (0/1 exact in bf16) and feat split hi/lo into two bf16
// fragments (error ~2^-18/elem) chained into the same f32 accumulator.
// No per-element LDS traffic at all (R4's ds_add_f32 path measured ~206
// cyc/wave-instr -> 593us; LDS atomics are not an accumulation path).
// Per wave: 32 accumulator VGPRs; one LDS-atomic merge (32 adds/lane) per
// block at the end, then 2048 global atomics per block.

#define BB 2
#define TT 8
#define CC 64
#define NVOX 110592      // 48*48*48
#define NREG 32
#define RS 33            // region slots incl. background 0
#define VW 512           // voxels per wave
#define BLKV 2048        // voxels per block (4 waves)
#define RSTR 65          // LDS reduce row stride (floats), odd -> spread banks

typedef __attribute__((ext_vector_type(8))) short bf16x8;
typedef __attribute__((ext_vector_type(4))) float f32x4;

static __device__ __forceinline__ unsigned short bf16_rn(float f) {
    unsigned u = __builtin_bit_cast(unsigned, f);
    u += 0x7FFFu + ((u >> 16) & 1u);
    return (unsigned short)(u >> 16);
}
static __device__ __forceinline__ float bf16_back(unsigned short h) {
    return __builtin_bit_cast(float, (unsigned)h << 16);
}
// split 8 consecutive f32 (two f32x4) into hi/lo bf16 fragments
static __device__ __forceinline__ void split8(f32x4 a, f32x4 b,
                                              bf16x8& hi, bf16x8& lo) {
    #pragma unroll
    for (int j = 0; j < 4; ++j) {
        float f = a[j];
        unsigned short h = bf16_rn(f);
        hi[j] = (short)h; lo[j] = (short)bf16_rn(f - bf16_back(h));
        f = b[j];
        h = bf16_rn(f);
        hi[j + 4] = (short)h; lo[j + 4] = (short)bf16_rn(f - bf16_back(h));
    }
}

// ---------------- kernel 1: per-batch region histogram -------------------
__global__ __launch_bounds__(256) void seg_hist(const int* __restrict__ seg,
                                                float* __restrict__ counts) {
    __shared__ float h[4 * RS];
    const int tid = threadIdx.x;
    const int w = tid >> 6;
    for (int i = tid; i < 4 * RS; i += 256) h[i] = 0.f;
    __syncthreads();

    const int base = blockIdx.x * 1024 + tid * 4;  // flattened over B*NVOX
    const int b = base / NVOX;                      // block fully inside one batch
    const int4 s4 = *(const int4*)(seg + base);
    atomicAdd(&h[w * RS + s4.x], 1.f);
    atomicAdd(&h[w * RS + s4.y], 1.f);
    atomicAdd(&h[w * RS + s4.z], 1.f);
    atomicAdd(&h[w * RS + s4.w], 1.f);
    __syncthreads();

    if (tid < RS) {
        const float v = h[tid] + h[RS + tid] + h[2 * RS + tid] + h[3 * RS + tid];
        atomicAdd(&counts[b * RS + tid], v);
    }
}

// ---------------- kernel 2: one-hot MFMA region sums ---------------------
// grid (NVOX/BLKV, T, B) = (54, 8, 2), block 256 (4 waves, disjoint voxels).
// mfma_f32_16x16x32_bf16: A[m=16 ch][k=32 vox], B[k=32 vox][n=16 reg].
// Lane l: A rows m=l&15, k-slots (l>>4)*8+j (8 consecutive voxels);
// B cols n=l&15, same k-slots. 4 ch-frags x 2 reg-frags x {hi,lo} = 16
// MFMA per 32 voxels into 8 f32x4 accumulators.
__global__ __launch_bounds__(256) void seg_sum(const float* __restrict__ feat,
                                               const int* __restrict__ seg,
                                               float* __restrict__ out) {
    __shared__ float red[NREG * RSTR];   // 8320 B
    const int tid = threadIdx.x;
    const int w = tid >> 6;
    const int l = tid & 63;
    const int lm = l & 15;          // channel-within-frag / region-within-frag
    const int kg = (l >> 4) * 8;    // this lane's voxel slot base (0/8/16/24)
    const int b = blockIdx.z;
    const int t = blockIdx.y;

    for (int i = tid; i < NREG * RSTR; i += 256) red[i] = 0.f;

    const int vw = blockIdx.x * BLKV + w * VW;
    const float* __restrict__ fp0 = feat + (size_t)(b * TT + t) * CC * NVOX
                                    + (size_t)lm * NVOX + vw + kg;
    const float* __restrict__ fp1 = fp0 + (size_t)16 * NVOX;
    const float* __restrict__ fp2 = fp0 + (size_t)32 * NVOX;
    const float* __restrict__ fp3 = fp0 + (size_t)48 * NVOX;
    const int* __restrict__ sp = seg + (size_t)b * NVOX + vw + kg;
    const int r0 = lm + 1;          // region id for B-frag 0
    const int r1 = lm + 17;         // region id for B-frag 1

    f32x4 a00 = {0.f, 0.f, 0.f, 0.f}, a01 = a00, a10 = a00, a11 = a00;
    f32x4 a20 = a00, a21 = a00, a30 = a00, a31 = a00;

    #pragma unroll 2
    for (int kv = 0; kv < VW; kv += 32) {
        const f32x4 q0a = *(const f32x4*)(fp0 + kv);
        const f32x4 q0b = *(const f32x4*)(fp0 + kv + 4);
        const f32x4 q1a = *(const f32x4*)(fp1 + kv);
        const f32x4 q1b = *(const f32x4*)(fp1 + kv + 4);
        const f32x4 q2a = *(const f32x4*)(fp2 + kv);
        const f32x4 q2b = *(const f32x4*)(fp2 + kv + 4);
        const f32x4 q3a = *(const f32x4*)(fp3 + kv);
        const f32x4 q3b = *(const f32x4*)(fp3 + kv + 4);
        const int4 s0 = *(const int4*)(sp + kv);
        const int4 s1 = *(const int4*)(sp + kv + 4);

        bf16x8 ah0, al0, ah1, al1, ah2, al2, ah3, al3, bv0, bv1;
        split8(q0a, q0b, ah0, al0);
        split8(q1a, q1b, ah1, al1);
        split8(q2a, q2b, ah2, al2);
        split8(q3a, q3b, ah3, al3);

        const int sv[8] = {s0.x, s0.y, s0.z, s0.w, s1.x, s1.y, s1.z, s1.w};
        #pragma unroll
        for (int j = 0; j < 8; ++j) {
            bv0[j] = (sv[j] == r0) ? (short)0x3F80 : (short)0;
            bv1[j] = (sv[j] == r1) ? (short)0x3F80 : (short)0;
        }

        a00 = __builtin_amdgcn_mfma_f32_16x16x32_bf16(ah0, bv0, a00, 0, 0, 0);
        a00 = __builtin_amdgcn_mfma_f32_16x16x32_bf16(al0, bv0, a00, 0, 0, 0);
        a01 = __builtin_amdgcn_mfma_f32_16x16x32_bf16(ah0, bv1, a01, 0, 0, 0);
        a01 = __builtin_amdgcn_mfma_f32_16x16x32_bf16(al0, bv1, a01, 0, 0, 0);
        a10 = __builtin_amdgcn_mfma_f32_16x16x32_bf16(ah1, bv0, a10, 0, 0, 0);
        a10 = __builtin_amdgcn_mfma_f32_16x16x32_bf16(al1, bv0, a10, 0, 0, 0);
        a11 = __builtin_amdgcn_mfma_f32_16x16x32_bf16(ah1, bv1, a11, 0, 0, 0);
        a11 = __builtin_amdgcn_mfma_f32_16x16x32_bf16(al1, bv1, a11, 0, 0, 0);
        a20 = __builtin_amdgcn_mfma_f32_16x16x32_bf16(ah2, bv0, a20, 0, 0, 0);
        a20 = __builtin_amdgcn_mfma_f32_16x16x32_bf16(al2, bv0, a20, 0, 0, 0);
        a21 = __builtin_amdgcn_mfma_f32_16x16x32_bf16(ah2, bv1, a21, 0, 0, 0);
        a21 = __builtin_amdgcn_mfma_f32_16x16x32_bf16(al2, bv1, a21, 0, 0, 0);
        a30 = __builtin_amdgcn_mfma_f32_16x16x32_bf16(ah3, bv0, a30, 0, 0, 0);
        a30 = __builtin_amdgcn_mfma_f32_16x16x32_bf16(al3, bv0, a30, 0, 0, 0);
        a31 = __builtin_amdgcn_mfma_f32_16x16x32_bf16(ah3, bv1, a31, 0, 0, 0);
        a31 = __builtin_amdgcn_mfma_f32_16x16x32_bf16(al3, bv1, a31, 0, 0, 0);
    }

    __syncthreads();   // red[] init visible; K-loop touched no LDS

    // D layout (m89-verified): col n = lane&15, row m = (lane>>4)*4 + reg.
    // acc[h][g][r] -> channel 16h + (l>>4)*4 + r, region-index g*16 + (l&15).
    const int rw = (l >> 4) * 4;
    #pragma unroll
    for (int r = 0; r < 4; ++r) {
        const int c = rw + r;
        atomicAdd(&red[(lm)      * RSTR + c],      a00[r]);
        atomicAdd(&red[(lm + 16) * RSTR + c],      a01[r]);
        atomicAdd(&red[(lm)      * RSTR + c + 16], a10[r]);
        atomicAdd(&red[(lm + 16) * RSTR + c + 16], a11[r]);
        atomicAdd(&red[(lm)      * RSTR + c + 32], a20[r]);
        atomicAdd(&red[(lm + 16) * RSTR + c + 32], a21[r]);
        atomicAdd(&red[(lm)      * RSTR + c + 48], a30[r]);
        atomicAdd(&red[(lm + 16) * RSTR + c + 48], a31[r]);
    }
    __syncthreads();

    // merge to global (region-index i>>6 corresponds to region id (i>>6)+1)
    float* __restrict__ outbt = out + (size_t)(b * TT + t) * NREG * CC;
    for (int i = tid; i < NREG * CC; i += 256) {
        atomicAdd(&outbt[i], red[(i >> 6) * RSTR + (i & 63)]);
    }
}

// ---------------- kernel 3: divide by counts -----------------------------
__global__ __launch_bounds__(256) void seg_div(float* __restrict__ out,
                                               const float* __restrict__ counts) {
    const int i = blockIdx.x * 256 + threadIdx.x;       // out_size = 32768
    const int b = i >> 14;                              // / (TT*NREG*CC)
    const int r = ((i >> 6) & 31) + 1;                  // region 1..32
    const float cnt = counts[b * RS + r];
    const float v = out[i];
    out[i] = cnt > 0.f ? v / cnt : 0.f;
}

extern "C" void kernel_launch(void* const* d_in, const int* in_sizes, int n_in,
                              void* d_out, int out_size, void* d_ws, size_t ws_size,
                              hipStream_t stream) {
    const float* feat = (const float*)d_in[0];
    const int* seg = (const int*)d_in[1];
    float* out = (float*)d_out;
    float* counts = (float*)d_ws;  // BB*RS floats

    hipMemsetAsync(d_out, 0, (size_t)out_size * sizeof(float), stream);
    hipMemsetAsync(d_ws, 0, (size_t)(BB * RS) * sizeof(float), stream);

    seg_hist<<<dim3((BB * NVOX) / 1024), 256, 0, stream>>>(seg, counts);
    seg_sum<<<dim3(NVOX / BLKV, TT, BB), 256, 0, stream>>>(feat, seg, out);
    seg_div<<<dim3(out_size / 256), 256, 0, stream>>>(out, counts);
}

// Round 4
// 655.315 us; speedup vs baseline: 1.5954x; 1.0045x over previous
//
#include <hip/hip_runtime.h>
#include <hip/hip_bf16.h>

// SubregionFeatureExtractor: per-batch, per-time, per-region channel means.
// features [B,T,C,D,H,W] f32, segmentation [B,1,D,H,W] int32 in 0..32.
// out [B,T,32,C] f32: mean over voxels with seg==r (r=1..32); empty -> 0.
//
// R7 = R6 with the compile fix (__hip_bfloat162 is not trivially copyable ->
// __builtin_memcpy instead of __builtin_bit_cast).
// R6: one-hot MFMA (R5) with the three overhead sources removed:
//  - NO atomics anywhere in the sum path: each wave stores its 32reg x 64ch
//    f32 partial tile to ws (8 coalesced dwordx4 stores); seg_div reduces the
//    432 wave-partials per (b,t) element (56 MB coalesced = ~9 us) + divides.
//  - hi/lo bf16 split via v_cvt_pk_bf16_f32 (__float22bfloat162_rn):
//    ~3 VALU/elem instead of ~9 (same RNE math, bit-identical output).
//  - 1728 blocks (6.75/CU, ~4% tail) + explicit 2-stage software pipeline
//    with named A/B load sets (static indexing only).

#define BB 2
#define TT 8
#define CC 64
#define NVOX 110592      // 48*48*48
#define NREG 32
#define RS 33            // region slots incl. background 0
#define VW 256           // voxels per wave
#define BLKV 1024        // voxels per block (4 waves)
#define NWBT 432         // waves per (b,t) = (NVOX/BLKV)*4
#define PART_OFF 2048    // float offset of partial buffer in ws (counts below)

typedef __attribute__((ext_vector_type(8))) short bf16x8;
typedef __attribute__((ext_vector_type(4))) float f32x4;

static __device__ __forceinline__ unsigned cvtpk(float x, float y) {
    __hip_bfloat162 h = __float22bfloat162_rn(make_float2(x, y));
    unsigned u;
    __builtin_memcpy(&u, &h, 4);
    return u;
}
static __device__ __forceinline__ float lowf(unsigned w)  { return __builtin_bit_cast(float, w << 16); }
static __device__ __forceinline__ float highf(unsigned w) { return __builtin_bit_cast(float, w & 0xFFFF0000u); }

struct HiLo { uint4 h, l; };
// 8 consecutive f32 -> hi bf16x8 (RNE) and lo bf16x8 (RNE of exact residual)
static __device__ __forceinline__ HiLo split8(const f32x4& a, const f32x4& b) {
    HiLo r;
    r.h.x = cvtpk(a[0], a[1]); r.h.y = cvtpk(a[2], a[3]);
    r.h.z = cvtpk(b[0], b[1]); r.h.w = cvtpk(b[2], b[3]);
    r.l.x = cvtpk(a[0] - lowf(r.h.x), a[1] - highf(r.h.x));
    r.l.y = cvtpk(a[2] - lowf(r.h.y), a[3] - highf(r.h.y));
    r.l.z = cvtpk(b[0] - lowf(r.h.z), b[1] - highf(r.h.z));
    r.l.w = cvtpk(b[2] - lowf(r.h.w), b[3] - highf(r.h.w));
    return r;
}
static __device__ __forceinline__ bf16x8 asbf(const uint4& u) {
    bf16x8 v;
    __builtin_memcpy(&v, &u, 16);
    return v;
}
// one-hot B fragment (1.0bf16 where seg==r) for this lane's 8 k-slots
static __device__ __forceinline__ bf16x8 bfrag(const int4& s0, const int4& s1, int r) {
    uint4 u;
    u.x = (s0.x == r ? 0x3F80u : 0u) | (s0.y == r ? 0x3F800000u : 0u);
    u.y = (s0.z == r ? 0x3F80u : 0u) | (s0.w == r ? 0x3F800000u : 0u);
    u.z = (s1.x == r ? 0x3F80u : 0u) | (s1.y == r ? 0x3F800000u : 0u);
    u.w = (s1.z == r ? 0x3F80u : 0u) | (s1.w == r ? 0x3F800000u : 0u);
    return asbf(u);
}

struct Ld {
    f32x4 q0a, q0b, q1a, q1b, q2a, q2b, q3a, q3b;
    int4 s0, s1;
};
static __device__ __forceinline__ void ldtile(Ld& L, const float* fp0, const float* fp1,
                                              const float* fp2, const float* fp3,
                                              const int* sp, int kv) {
    L.q0a = *(const f32x4*)(fp0 + kv); L.q0b = *(const f32x4*)(fp0 + kv + 4);
    L.q1a = *(const f32x4*)(fp1 + kv); L.q1b = *(const f32x4*)(fp1 + kv + 4);
    L.q2a = *(const f32x4*)(fp2 + kv); L.q2b = *(const f32x4*)(fp2 + kv + 4);
    L.q3a = *(const f32x4*)(fp3 + kv); L.q3b = *(const f32x4*)(fp3 + kv + 4);
    L.s0 = *(const int4*)(sp + kv);    L.s1 = *(const int4*)(sp + kv + 4);
}
#define MFMA __builtin_amdgcn_mfma_f32_16x16x32_bf16
static __device__ __forceinline__ void proc(const Ld& L, int r0, int r1,
        f32x4& a00, f32x4& a01, f32x4& a10, f32x4& a11,
        f32x4& a20, f32x4& a21, f32x4& a30, f32x4& a31) {
    const bf16x8 b0 = bfrag(L.s0, L.s1, r0);
    const bf16x8 b1 = bfrag(L.s0, L.s1, r1);
    const HiLo h0 = split8(L.q0a, L.q0b);
    const HiLo h1 = split8(L.q1a, L.q1b);
    const HiLo h2 = split8(L.q2a, L.q2b);
    const HiLo h3 = split8(L.q3a, L.q3b);
    a00 = MFMA(asbf(h0.h), b0, a00, 0, 0, 0);
    a00 = MFMA(asbf(h0.l), b0, a00, 0, 0, 0);
    a01 = MFMA(asbf(h0.h), b1, a01, 0, 0, 0);
    a01 = MFMA(asbf(h0.l), b1, a01, 0, 0, 0);
    a10 = MFMA(asbf(h1.h), b0, a10, 0, 0, 0);
    a10 = MFMA(asbf(h1.l), b0, a10, 0, 0, 0);
    a11 = MFMA(asbf(h1.h), b1, a11, 0, 0, 0);
    a11 = MFMA(asbf(h1.l), b1, a11, 0, 0, 0);
    a20 = MFMA(asbf(h2.h), b0, a20, 0, 0, 0);
    a20 = MFMA(asbf(h2.l), b0, a20, 0, 0, 0);
    a21 = MFMA(asbf(h2.h), b1, a21, 0, 0, 0);
    a21 = MFMA(asbf(h2.l), b1, a21, 0, 0, 0);
    a30 = MFMA(asbf(h3.h), b0, a30, 0, 0, 0);
    a30 = MFMA(asbf(h3.l), b0, a30, 0, 0, 0);
    a31 = MFMA(asbf(h3.h), b1, a31, 0, 0, 0);
    a31 = MFMA(asbf(h3.l), b1, a31, 0, 0, 0);
}

// ---------------- kernel 1: per-batch region histogram -------------------
__global__ __launch_bounds__(256) void seg_hist(const int* __restrict__ seg,
                                                float* __restrict__ counts) {
    __shared__ float h[4 * RS];
    const int tid = threadIdx.x;
    const int w = tid >> 6;
    for (int i = tid; i < 4 * RS; i += 256) h[i] = 0.f;
    __syncthreads();

    const int base = blockIdx.x * 1024 + tid * 4;  // flattened over B*NVOX
    const int b = base / NVOX;                      // block fully inside one batch
    const int4 s4 = *(const int4*)(seg + base);
    atomicAdd(&h[w * RS + s4.x], 1.f);
    atomicAdd(&h[w * RS + s4.y], 1.f);
    atomicAdd(&h[w * RS + s4.z], 1.f);
    atomicAdd(&h[w * RS + s4.w], 1.f);
    __syncthreads();

    if (tid < RS) {
        const float v = h[tid] + h[RS + tid] + h[2 * RS + tid] + h[3 * RS + tid];
        atomicAdd(&counts[b * RS + tid], v);
    }
}

// ---------------- kernel 2: one-hot MFMA region sums ---------------------
// grid (NVOX/BLKV, T, B) = (108, 8, 2), block 256 (4 waves, disjoint voxels).
// Lane l: A rows m=l&15 (channel), 8 consecutive voxels at kg=(l>>4)*8;
// B cols n=l&15 (region), same voxel slots. 16 MFMA per 32 voxels.
// Ends with 8 coalesced f32x4 stores of the wave's [32reg][64ch] partial.
__global__ __launch_bounds__(256) void seg_sum(const float* __restrict__ feat,
                                               const int* __restrict__ seg,
                                               float* __restrict__ part) {
    const int tid = threadIdx.x;
    const int w = tid >> 6;
    const int l = tid & 63;
    const int lm = l & 15;
    const int kg = (l >> 4) * 8;
    const int b = blockIdx.z;
    const int t = blockIdx.y;

    const int vw = blockIdx.x * BLKV + w * VW;
    const float* __restrict__ fp0 = feat + (size_t)(b * TT + t) * CC * NVOX
                                    + (size_t)lm * NVOX + vw + kg;
    const float* __restrict__ fp1 = fp0 + (size_t)16 * NVOX;
    const float* __restrict__ fp2 = fp0 + (size_t)32 * NVOX;
    const float* __restrict__ fp3 = fp0 + (size_t)48 * NVOX;
    const int* __restrict__ sp = seg + (size_t)b * NVOX + vw + kg;
    const int r0 = lm + 1;
    const int r1 = lm + 17;

    f32x4 a00 = {0.f, 0.f, 0.f, 0.f}, a01 = a00, a10 = a00, a11 = a00;
    f32x4 a20 = a00, a21 = a00, a30 = a00, a31 = a00;

    Ld A, B;
    ldtile(A, fp0, fp1, fp2, fp3, sp, 0);
    #pragma unroll 1
    for (int j = 0; j < 3; ++j) {
        ldtile(B, fp0, fp1, fp2, fp3, sp, j * 64 + 32);
        proc(A, r0, r1, a00, a01, a10, a11, a20, a21, a30, a31);
        ldtile(A, fp0, fp1, fp2, fp3, sp, j * 64 + 64);
        proc(B, r0, r1, a00, a01, a10, a11, a20, a21, a30, a31);
    }
    ldtile(B, fp0, fp1, fp2, fp3, sp, 224);
    proc(A, r0, r1, a00, a01, a10, a11, a20, a21, a30, a31);
    proc(B, r0, r1, a00, a01, a10, a11, a20, a21, a30, a31);

    // D layout (m89): col n = lane&15 (region idx), row m = (l>>4)*4 + r (ch).
    // Partial tile layout [reg idx 0..31][ch 0..63]; a-row r gives 4
    // consecutive channels -> f32x4 stores, 64 lanes cover the 8KB tile.
    const int wbt = blockIdx.x * 4 + w;   // wave index within (b,t), 0..431
    float* __restrict__ p = part + ((size_t)(b * TT + t) * NWBT + wbt) * 2048;
    const int rw = (l >> 4) * 4;
    *(f32x4*)(p + lm * 64 + rw)             = a00;
    *(f32x4*)(p + (lm + 16) * 64 + rw)      = a01;
    *(f32x4*)(p + lm * 64 + rw + 16)        = a10;
    *(f32x4*)(p + (lm + 16) * 64 + rw + 16) = a11;
    *(f32x4*)(p + lm * 64 + rw + 32)        = a20;
    *(f32x4*)(p + (lm + 16) * 64 + rw + 32) = a21;
    *(f32x4*)(p + lm * 64 + rw + 48)        = a30;
    *(f32x4*)(p + (lm + 16) * 64 + rw + 48) = a31;
}

// ---------------- kernel 3: reduce partials + divide by counts -----------
// grid 512 x block 64: thread i owns one output element; sums 432 wave
// partials (stride 2048 floats, coalesced across the 64-lane block).
__global__ __launch_bounds__(64) void seg_div(const float* __restrict__ part,
                                              const float* __restrict__ counts,
                                              float* __restrict__ out) {
    const int i = blockIdx.x * 64 + threadIdx.x;   // 0..32767
    const int bt = i >> 11;                         // / (NREG*CC)
    const int b = i >> 14;
    const int r = ((i >> 6) & 31) + 1;              // region id 1..32
    const float* __restrict__ p = part + (size_t)bt * NWBT * 2048 + (i & 2047);
    float s0 = 0.f, s1 = 0.f, s2 = 0.f, s3 = 0.f;
    #pragma unroll 4
    for (int j = 0; j < NWBT; j += 4) {
        s0 += p[j * 2048];       s1 += p[(j + 1) * 2048];
        s2 += p[(j + 2) * 2048]; s3 += p[(j + 3) * 2048];
    }
    const float cnt = counts[b * RS + r];
    out[i] = cnt > 0.f ? ((s0 + s1) + (s2 + s3)) / cnt : 0.f;
}

extern "C" void kernel_launch(void* const* d_in, const int* in_sizes, int n_in,
                              void* d_out, int out_size, void* d_ws, size_t ws_size,
                              hipStream_t stream) {
    const float* feat = (const float*)d_in[0];
    const int* seg = (const int*)d_in[1];
    float* out = (float*)d_out;
    float* counts = (float*)d_ws;                   // BB*RS floats
    float* part = (float*)d_ws + PART_OFF;          // 16*432*2048 floats (~57 MB)

    (void)hipMemsetAsync(d_ws, 0, (size_t)(BB * RS) * sizeof(float), stream);

    seg_hist<<<dim3((BB * NVOX) / 1024), 256, 0, stream>>>(seg, counts);
    seg_sum<<<dim3(NVOX / BLKV, TT, BB), 256, 0, stream>>>(feat, seg, part);
    seg_div<<<dim3(out_size / 64), 64, 0, stream>>>(part, counts, out);
}

// Round 5
// 610.618 us; speedup vs baseline: 1.7122x; 1.0732x over previous
//
#include <hip/hip_runtime.h>
#include <hip/hip_bf16.h>

// SubregionFeatureExtractor: per-batch, per-time, per-region channel means.
// features [B,T,C,D,H,W] f32, segmentation [B,1,D,H,W] int32 in 0..32.
// out [B,T,32,C] f32: mean over voxels with seg==r (r=1..32); empty -> 0.
//
// R8 = R7 (one-hot hi/lo bf16 MFMA, no atomics) + merge-path fixes:
//  - in-block LDS merge of the 4 wave tiles (plain stores at stride 68,
//    2-way banks = free; one __syncthreads; thread sums 4 copies) ->
//    partials drop 432 -> 108 per (b,t): 57 MB -> 14 MB of ws traffic.
//  - seg_div now sums only 108 partials (27 x 4-deep ILP, data L2/L3-hot).
// seg_sum K-loop is byte-identical to R7.

#define BB 2
#define TT 8
#define CC 64
#define NVOX 110592      // 48*48*48
#define NREG 32
#define RS 33            // region slots incl. background 0
#define VW 256           // voxels per wave
#define BLKV 1024        // voxels per block (4 waves)
#define NBBT 108         // block partials per (b,t) = NVOX/BLKV
#define PART_OFF 2048    // float offset of partial buffer in ws
#define MST 68           // LDS merge row stride (floats): 68%32=4 -> 2-way banks
#define MCP 2176         // floats per wave copy = 32*MST

typedef __attribute__((ext_vector_type(8))) short bf16x8;
typedef __attribute__((ext_vector_type(4))) float f32x4;

static __device__ __forceinline__ unsigned cvtpk(float x, float y) {
    __hip_bfloat162 h = __float22bfloat162_rn(make_float2(x, y));
    unsigned u;
    __builtin_memcpy(&u, &h, 4);
    return u;
}
static __device__ __forceinline__ float lowf(unsigned w)  { return __builtin_bit_cast(float, w << 16); }
static __device__ __forceinline__ float highf(unsigned w) { return __builtin_bit_cast(float, w & 0xFFFF0000u); }

struct HiLo { uint4 h, l; };
// 8 consecutive f32 -> hi bf16x8 (RNE) and lo bf16x8 (RNE of exact residual)
static __device__ __forceinline__ HiLo split8(const f32x4& a, const f32x4& b) {
    HiLo r;
    r.h.x = cvtpk(a[0], a[1]); r.h.y = cvtpk(a[2], a[3]);
    r.h.z = cvtpk(b[0], b[1]); r.h.w = cvtpk(b[2], b[3]);
    r.l.x = cvtpk(a[0] - lowf(r.h.x), a[1] - highf(r.h.x));
    r.l.y = cvtpk(a[2] - lowf(r.h.y), a[3] - highf(r.h.y));
    r.l.z = cvtpk(b[0] - lowf(r.h.z), b[1] - highf(r.h.z));
    r.l.w = cvtpk(b[2] - lowf(r.h.w), b[3] - highf(r.h.w));
    return r;
}
static __device__ __forceinline__ bf16x8 asbf(const uint4& u) {
    bf16x8 v;
    __builtin_memcpy(&v, &u, 16);
    return v;
}
// one-hot B fragment (1.0bf16 where seg==r) for this lane's 8 k-slots
static __device__ __forceinline__ bf16x8 bfrag(const int4& s0, const int4& s1, int r) {
    uint4 u;
    u.x = (s0.x == r ? 0x3F80u : 0u) | (s0.y == r ? 0x3F800000u : 0u);
    u.y = (s0.z == r ? 0x3F80u : 0u) | (s0.w == r ? 0x3F800000u : 0u);
    u.z = (s1.x == r ? 0x3F80u : 0u) | (s1.y == r ? 0x3F800000u : 0u);
    u.w = (s1.z == r ? 0x3F80u : 0u) | (s1.w == r ? 0x3F800000u : 0u);
    return asbf(u);
}

struct Ld {
    f32x4 q0a, q0b, q1a, q1b, q2a, q2b, q3a, q3b;
    int4 s0, s1;
};
static __device__ __forceinline__ void ldtile(Ld& L, const float* fp0, const float* fp1,
                                              const float* fp2, const float* fp3,
                                              const int* sp, int kv) {
    L.q0a = *(const f32x4*)(fp0 + kv); L.q0b = *(const f32x4*)(fp0 + kv + 4);
    L.q1a = *(const f32x4*)(fp1 + kv); L.q1b = *(const f32x4*)(fp1 + kv + 4);
    L.q2a = *(const f32x4*)(fp2 + kv); L.q2b = *(const f32x4*)(fp2 + kv + 4);
    L.q3a = *(const f32x4*)(fp3 + kv); L.q3b = *(const f32x4*)(fp3 + kv + 4);
    L.s0 = *(const int4*)(sp + kv);    L.s1 = *(const int4*)(sp + kv + 4);
}
#define MFMA __builtin_amdgcn_mfma_f32_16x16x32_bf16
static __device__ __forceinline__ void proc(const Ld& L, int r0, int r1,
        f32x4& a00, f32x4& a01, f32x4& a10, f32x4& a11,
        f32x4& a20, f32x4& a21, f32x4& a30, f32x4& a31) {
    const bf16x8 b0 = bfrag(L.s0, L.s1, r0);
    const bf16x8 b1 = bfrag(L.s0, L.s1, r1);
    const HiLo h0 = split8(L.q0a, L.q0b);
    const HiLo h1 = split8(L.q1a, L.q1b);
    const HiLo h2 = split8(L.q2a, L.q2b);
    const HiLo h3 = split8(L.q3a, L.q3b);
    a00 = MFMA(asbf(h0.h), b0, a00, 0, 0, 0);
    a00 = MFMA(asbf(h0.l), b0, a00, 0, 0, 0);
    a01 = MFMA(asbf(h0.h), b1, a01, 0, 0, 0);
    a01 = MFMA(asbf(h0.l), b1, a01, 0, 0, 0);
    a10 = MFMA(asbf(h1.h), b0, a10, 0, 0, 0);
    a10 = MFMA(asbf(h1.l), b0, a10, 0, 0, 0);
    a11 = MFMA(asbf(h1.h), b1, a11, 0, 0, 0);
    a11 = MFMA(asbf(h1.l), b1, a11, 0, 0, 0);
    a20 = MFMA(asbf(h2.h), b0, a20, 0, 0, 0);
    a20 = MFMA(asbf(h2.l), b0, a20, 0, 0, 0);
    a21 = MFMA(asbf(h2.h), b1, a21, 0, 0, 0);
    a21 = MFMA(asbf(h2.l), b1, a21, 0, 0, 0);
    a30 = MFMA(asbf(h3.h), b0, a30, 0, 0, 0);
    a30 = MFMA(asbf(h3.l), b0, a30, 0, 0, 0);
    a31 = MFMA(asbf(h3.h), b1, a31, 0, 0, 0);
    a31 = MFMA(asbf(h3.l), b1, a31, 0, 0, 0);
}

// ---------------- kernel 1: per-batch region histogram -------------------
__global__ __launch_bounds__(256) void seg_hist(const int* __restrict__ seg,
                                                float* __restrict__ counts) {
    __shared__ float h[4 * RS];
    const int tid = threadIdx.x;
    const int w = tid >> 6;
    for (int i = tid; i < 4 * RS; i += 256) h[i] = 0.f;
    __syncthreads();

    const int base = blockIdx.x * 1024 + tid * 4;  // flattened over B*NVOX
    const int b = base / NVOX;                      // block fully inside one batch
    const int4 s4 = *(const int4*)(seg + base);
    atomicAdd(&h[w * RS + s4.x], 1.f);
    atomicAdd(&h[w * RS + s4.y], 1.f);
    atomicAdd(&h[w * RS + s4.z], 1.f);
    atomicAdd(&h[w * RS + s4.w], 1.f);
    __syncthreads();

    if (tid < RS) {
        const float v = h[tid] + h[RS + tid] + h[2 * RS + tid] + h[3 * RS + tid];
        atomicAdd(&counts[b * RS + tid], v);
    }
}

// ---------------- kernel 2: one-hot MFMA region sums ---------------------
// grid (NVOX/BLKV, T, B) = (108, 8, 2), block 256 (4 waves, disjoint voxels).
// Lane l: A rows m=l&15 (channel), 8 consecutive voxels at kg=(l>>4)*8;
// B cols n=l&15 (region), same voxel slots. 16 MFMA per 32 voxels.
// Epilogue: 4 wave tiles merged in LDS (no atomics), ONE 8KB block partial.
__global__ __launch_bounds__(256) void seg_sum(const float* __restrict__ feat,
                                               const int* __restrict__ seg,
                                               float* __restrict__ part) {
    __shared__ float sm[4 * MCP];   // 34816 B
    const int tid = threadIdx.x;
    const int w = tid >> 6;
    const int l = tid & 63;
    const int lm = l & 15;
    const int kg = (l >> 4) * 8;
    const int b = blockIdx.z;
    const int t = blockIdx.y;

    const int vw = blockIdx.x * BLKV + w * VW;
    const float* __restrict__ fp0 = feat + (size_t)(b * TT + t) * CC * NVOX
                                    + (size_t)lm * NVOX + vw + kg;
    const float* __restrict__ fp1 = fp0 + (size_t)16 * NVOX;
    const float* __restrict__ fp2 = fp0 + (size_t)32 * NVOX;
    const float* __restrict__ fp3 = fp0 + (size_t)48 * NVOX;
    const int* __restrict__ sp = seg + (size_t)b * NVOX + vw + kg;
    const int r0 = lm + 1;
    const int r1 = lm + 17;

    f32x4 a00 = {0.f, 0.f, 0.f, 0.f}, a01 = a00, a10 = a00, a11 = a00;
    f32x4 a20 = a00, a21 = a00, a30 = a00, a31 = a00;

    Ld A, B;
    ldtile(A, fp0, fp1, fp2, fp3, sp, 0);
    #pragma unroll 1
    for (int j = 0; j < 3; ++j) {
        ldtile(B, fp0, fp1, fp2, fp3, sp, j * 64 + 32);
        proc(A, r0, r1, a00, a01, a10, a11, a20, a21, a30, a31);
        ldtile(A, fp0, fp1, fp2, fp3, sp, j * 64 + 64);
        proc(B, r0, r1, a00, a01, a10, a11, a20, a21, a30, a31);
    }
    ldtile(B, fp0, fp1, fp2, fp3, sp, 224);
    proc(A, r0, r1, a00, a01, a10, a11, a20, a21, a30, a31);
    proc(B, r0, r1, a00, a01, a10, a11, a20, a21, a30, a31);

    // D layout (m89): col n = lane&15 (region idx), row m = (l>>4)*4 + r (ch).
    // Wave tile [32 reg][64 ch] at row stride MST=68 (banks advance 4/row ->
    // 2-way = free). f32x4 stores: 4 consecutive channels per acc row.
    float* __restrict__ mt = sm + w * MCP;
    const int rw = (l >> 4) * 4;
    *(f32x4*)(mt + lm * MST + rw)             = a00;
    *(f32x4*)(mt + (lm + 16) * MST + rw)      = a01;
    *(f32x4*)(mt + lm * MST + rw + 16)        = a10;
    *(f32x4*)(mt + (lm + 16) * MST + rw + 16) = a11;
    *(f32x4*)(mt + lm * MST + rw + 32)        = a20;
    *(f32x4*)(mt + (lm + 16) * MST + rw + 32) = a21;
    *(f32x4*)(mt + lm * MST + rw + 48)        = a30;
    *(f32x4*)(mt + (lm + 16) * MST + rw + 48) = a31;
    __syncthreads();

    // merge 4 copies -> one [32reg][64ch] partial per block, coalesced f32x4.
    float* __restrict__ p = part + ((size_t)(b * TT + t) * NBBT + blockIdx.x) * 2048;
    #pragma unroll
    for (int h = 0; h < 2; ++h) {
        const int e = tid * 4 + h * 1024;              // element in [reg][ch]
        const int idx = (e >> 6) * MST + (e & 63);
        const f32x4 v0 = *(const f32x4*)(sm + idx);
        const f32x4 v1 = *(const f32x4*)(sm + MCP + idx);
        const f32x4 v2 = *(const f32x4*)(sm + 2 * MCP + idx);
        const f32x4 v3 = *(const f32x4*)(sm + 3 * MCP + idx);
        *(f32x4*)(p + e) = (v0 + v1) + (v2 + v3);
    }
}

// ---------------- kernel 3: reduce partials + divide by counts -----------
// grid 512 x block 64: thread i owns one output element; sums 108 block
// partials (stride 2048 floats, coalesced across the 64-lane wave).
__global__ __launch_bounds__(64) void seg_div(const float* __restrict__ part,
                                              const float* __restrict__ counts,
                                              float* __restrict__ out) {
    const int i = blockIdx.x * 64 + threadIdx.x;   // 0..32767
    const int bt = i >> 11;                         // / (NREG*CC)
    const int b = i >> 14;
    const int r = ((i >> 6) & 31) + 1;              // region id 1..32
    const float* __restrict__ p = part + (size_t)bt * NBBT * 2048 + (i & 2047);
    float s0 = 0.f, s1 = 0.f, s2 = 0.f, s3 = 0.f;
    #pragma unroll 4
    for (int j = 0; j < NBBT; j += 4) {
        s0 += p[j * 2048];       s1 += p[(j + 1) * 2048];
        s2 += p[(j + 2) * 2048]; s3 += p[(j + 3) * 2048];
    }
    const float cnt = counts[b * RS + r];
    out[i] = cnt > 0.f ? ((s0 + s1) + (s2 + s3)) / cnt : 0.f;
}

extern "C" void kernel_launch(void* const* d_in, const int* in_sizes, int n_in,
                              void* d_out, int out_size, void* d_ws, size_t ws_size,
                              hipStream_t stream) {
    const float* feat = (const float*)d_in[0];
    const int* seg = (const int*)d_in[1];
    float* out = (float*)d_out;
    float* counts = (float*)d_ws;                   // BB*RS floats
    float* part = (float*)d_ws + PART_OFF;          // 16*108*2048 floats (~14 MB)

    (void)hipMemsetAsync(d_ws, 0, (size_t)(BB * RS) * sizeof(float), stream);

    seg_hist<<<dim3((BB * NVOX) / 1024), 256, 0, stream>>>(seg, counts);
    seg_sum<<<dim3(NVOX / BLKV, TT, BB), 256, 0, stream>>>(feat, seg, part);
    seg_div<<<dim3(out_size / 64), 64, 0, stream>>>(part, counts, out);
}

// Round 6
// 610.096 us; speedup vs baseline: 1.7136x; 1.0009x over previous
//
#include <hip/hip_runtime.h>
#include <hip/hip_bf16.h>

// SubregionFeatureExtractor: per-batch, per-time, per-region channel means.
// features [B,T,C,D,H,W] f32, segmentation [B,1,D,H,W] int32 in 0..32.
// out [B,T,32,C] f32: mean over voxels with seg==r (r=1..32); empty -> 0.
//
// R9 = R8 (one-hot hi/lo bf16 MFMA, no atomics) restructured for occupancy +
// pipeline depth (theory: R8 was ~2 waves/SIMD, depth-1 prefetch -> ~350cy
// HBM-latency stall per tile):
//  - wave = 32 channels x 512 voxels (2 feat streams): Ld set 24 VGPR,
//    acc 16 VGPR; block = 2 ch-halves x 2 vox-halves (same 1024-vox tile).
//  - triple-buffered, statically unrolled 16-tile loop (depth-2 prefetch,
//    all load offsets compile-time immediates).
//  - __launch_bounds__(256, 4): cap 128 VGPR -> 4 waves/SIMD.
//  - LDS merge 17.4 KB (2 vox-copies; ch-halves are disjoint columns).

#define BB 2
#define TT 8
#define CC 64
#define NVOX 110592      // 48*48*48
#define NREG 32
#define RS 33            // region slots incl. background 0
#define BLKV 1024        // voxels per block
#define NBBT 108         // block partials per (b,t) = NVOX/BLKV
#define PART_OFF 2048    // float offset of partial buffer in ws
#define MST 68           // LDS merge row stride (floats)

typedef __attribute__((ext_vector_type(8))) short bf16x8;
typedef __attribute__((ext_vector_type(4))) float f32x4;

static __device__ __forceinline__ unsigned cvtpk(float x, float y) {
    __hip_bfloat162 h = __float22bfloat162_rn(make_float2(x, y));
    unsigned u;
    __builtin_memcpy(&u, &h, 4);
    return u;
}
static __device__ __forceinline__ float lowf(unsigned w)  { return __builtin_bit_cast(float, w << 16); }
static __device__ __forceinline__ float highf(unsigned w) { return __builtin_bit_cast(float, w & 0xFFFF0000u); }

struct HiLo { uint4 h, l; };
// 8 consecutive f32 -> hi bf16x8 (RNE) and lo bf16x8 (RNE of exact residual)
static __device__ __forceinline__ HiLo split8(const f32x4& a, const f32x4& b) {
    HiLo r;
    r.h.x = cvtpk(a[0], a[1]); r.h.y = cvtpk(a[2], a[3]);
    r.h.z = cvtpk(b[0], b[1]); r.h.w = cvtpk(b[2], b[3]);
    r.l.x = cvtpk(a[0] - lowf(r.h.x), a[1] - highf(r.h.x));
    r.l.y = cvtpk(a[2] - lowf(r.h.y), a[3] - highf(r.h.y));
    r.l.z = cvtpk(b[0] - lowf(r.h.z), b[1] - highf(r.h.z));
    r.l.w = cvtpk(b[2] - lowf(r.h.w), b[3] - highf(r.h.w));
    return r;
}
static __device__ __forceinline__ bf16x8 asbf(const uint4& u) {
    bf16x8 v;
    __builtin_memcpy(&v, &u, 16);
    return v;
}
// one-hot B fragment (1.0bf16 where seg==r) for this lane's 8 k-slots
static __device__ __forceinline__ bf16x8 bfrag(const int4& s0, const int4& s1, int r) {
    uint4 u;
    u.x = (s0.x == r ? 0x3F80u : 0u) | (s0.y == r ? 0x3F800000u : 0u);
    u.y = (s0.z == r ? 0x3F80u : 0u) | (s0.w == r ? 0x3F800000u : 0u);
    u.z = (s1.x == r ? 0x3F80u : 0u) | (s1.y == r ? 0x3F800000u : 0u);
    u.w = (s1.z == r ? 0x3F80u : 0u) | (s1.w == r ? 0x3F800000u : 0u);
    return asbf(u);
}

struct Ld2 { f32x4 q0a, q0b, q1a, q1b; int4 s0, s1; };   // 24 VGPR
#define MFMA __builtin_amdgcn_mfma_f32_16x16x32_bf16

static __device__ __forceinline__ void ldt(Ld2& L, const float* fp0, const float* fp1,
                                           const int* sp, int kv) {
    L.q0a = *(const f32x4*)(fp0 + kv); L.q0b = *(const f32x4*)(fp0 + kv + 4);
    L.q1a = *(const f32x4*)(fp1 + kv); L.q1b = *(const f32x4*)(fp1 + kv + 4);
    L.s0 = *(const int4*)(sp + kv);    L.s1 = *(const int4*)(sp + kv + 4);
}
static __device__ __forceinline__ void proc2(const Ld2& L, int r0, int r1,
        f32x4& a00, f32x4& a01, f32x4& a10, f32x4& a11) {
    const bf16x8 b0 = bfrag(L.s0, L.s1, r0);
    const bf16x8 b1 = bfrag(L.s0, L.s1, r1);
    const HiLo h0 = split8(L.q0a, L.q0b);
    const HiLo h1 = split8(L.q1a, L.q1b);
    a00 = MFMA(asbf(h0.h), b0, a00, 0, 0, 0);
    a00 = MFMA(asbf(h0.l), b0, a00, 0, 0, 0);
    a01 = MFMA(asbf(h0.h), b1, a01, 0, 0, 0);
    a01 = MFMA(asbf(h0.l), b1, a01, 0, 0, 0);
    a10 = MFMA(asbf(h1.h), b0, a10, 0, 0, 0);
    a10 = MFMA(asbf(h1.l), b0, a10, 0, 0, 0);
    a11 = MFMA(asbf(h1.h), b1, a11, 0, 0, 0);
    a11 = MFMA(asbf(h1.l), b1, a11, 0, 0, 0);
}

// ---------------- kernel 1: per-batch region histogram -------------------
__global__ __launch_bounds__(256) void seg_hist(const int* __restrict__ seg,
                                                float* __restrict__ counts) {
    __shared__ float h[4 * RS];
    const int tid = threadIdx.x;
    const int w = tid >> 6;
    for (int i = tid; i < 4 * RS; i += 256) h[i] = 0.f;
    __syncthreads();

    const int base = blockIdx.x * 1024 + tid * 4;  // flattened over B*NVOX
    const int b = base / NVOX;                      // block fully inside one batch
    const int4 s4 = *(const int4*)(seg + base);
    atomicAdd(&h[w * RS + s4.x], 1.f);
    atomicAdd(&h[w * RS + s4.y], 1.f);
    atomicAdd(&h[w * RS + s4.z], 1.f);
    atomicAdd(&h[w * RS + s4.w], 1.f);
    __syncthreads();

    if (tid < RS) {
        const float v = h[tid] + h[RS + tid] + h[2 * RS + tid] + h[3 * RS + tid];
        atomicAdd(&counts[b * RS + tid], v);
    }
}

// ---------------- kernel 2: one-hot MFMA region sums ---------------------
// grid (NVOX/BLKV, T, B) = (108, 8, 2), block 256.
// Wave w: ch-half h=w&1 (32 channels), vox-half v=w>>1 (512 voxels, 16 tiles).
// Lane l: A rows m=l&15 (channel), 8 consecutive voxels at kg=(l>>4)*8;
// B cols n=l&15 (region), same voxel slots. 8 MFMA per 32-voxel tile.
__global__ __launch_bounds__(256, 4) void seg_sum(const float* __restrict__ feat,
                                                  const int* __restrict__ seg,
                                                  float* __restrict__ part) {
    __shared__ float sm[2 * NREG * MST];   // 17408 B
    const int tid = threadIdx.x;
    const int w = tid >> 6;
    const int l = tid & 63;
    const int lm = l & 15;
    const int kg = (l >> 4) * 8;
    const int h = w & 1;        // channel half (ch 32h .. 32h+31)
    const int v = w >> 1;       // voxel half
    const int b = blockIdx.z;
    const int t = blockIdx.y;

    const int vw = blockIdx.x * BLKV + v * 512;
    const float* __restrict__ fp0 = feat + (size_t)(b * TT + t) * CC * NVOX
                                    + (size_t)(32 * h + lm) * NVOX + vw + kg;
    const float* __restrict__ fp1 = fp0 + (size_t)16 * NVOX;
    const int* __restrict__ sp = seg + (size_t)b * NVOX + vw + kg;
    const int r0 = lm + 1;
    const int r1 = lm + 17;

    f32x4 a00 = {0.f, 0.f, 0.f, 0.f}, a01 = a00, a10 = a00, a11 = a00;

    // 16 tiles of 32 voxels; triple-buffer, depth-2 prefetch, static offsets.
    Ld2 S0, S1, S2;
    #define LDJ(S, J)  ldt(S, fp0, fp1, sp, (J) * 32)
    #define PRC(S)     proc2(S, r0, r1, a00, a01, a10, a11)
    LDJ(S0, 0); LDJ(S1, 1);
    PRC(S0); LDJ(S2, 2);
    PRC(S1); LDJ(S0, 3);
    PRC(S2); LDJ(S1, 4);
    PRC(S0); LDJ(S2, 5);
    PRC(S1); LDJ(S0, 6);
    PRC(S2); LDJ(S1, 7);
    PRC(S0); LDJ(S2, 8);
    PRC(S1); LDJ(S0, 9);
    PRC(S2); LDJ(S1, 10);
    PRC(S0); LDJ(S2, 11);
    PRC(S1); LDJ(S0, 12);
    PRC(S2); LDJ(S1, 13);
    PRC(S0); LDJ(S2, 14);
    PRC(S1); LDJ(S0, 15);
    PRC(S2);
    PRC(S0);
    #undef LDJ
    #undef PRC

    // D layout (m89): col n = lane&15 (region idx), row m = (l>>4)*4 + e (ch).
    // sm[v][reg 32][ch 64 + pad]; ch-halves write disjoint columns.
    float* __restrict__ mt = sm + v * (NREG * MST);
    const int cb = 32 * h + (l >> 4) * 4;
    *(f32x4*)(mt + lm * MST + cb)             = a00;
    *(f32x4*)(mt + (lm + 16) * MST + cb)      = a01;
    *(f32x4*)(mt + lm * MST + cb + 16)        = a10;
    *(f32x4*)(mt + (lm + 16) * MST + cb + 16) = a11;
    __syncthreads();

    // merge 2 vox-copies -> one [32reg][64ch] partial per block, coalesced.
    float* __restrict__ p = part + ((size_t)(b * TT + t) * NBBT + blockIdx.x) * 2048;
    #pragma unroll
    for (int g = 0; g < 2; ++g) {
        const int e = tid * 4 + g * 1024;              // element in [reg][ch]
        const int idx = (e >> 6) * MST + (e & 63);
        const f32x4 v0 = *(const f32x4*)(sm + idx);
        const f32x4 v1 = *(const f32x4*)(sm + NREG * MST + idx);
        *(f32x4*)(p + e) = v0 + v1;
    }
}

// ---------------- kernel 3: reduce partials + divide by counts -----------
// grid 512 x block 64: thread i owns one output element; sums 108 block
// partials (stride 2048 floats, coalesced across the 64-lane wave).
__global__ __launch_bounds__(64) void seg_div(const float* __restrict__ part,
                                              const float* __restrict__ counts,
                                              float* __restrict__ out) {
    const int i = blockIdx.x * 64 + threadIdx.x;   // 0..32767
    const int bt = i >> 11;                         // / (NREG*CC)
    const int b = i >> 14;
    const int r = ((i >> 6) & 31) + 1;              // region id 1..32
    const float* __restrict__ p = part + (size_t)bt * NBBT * 2048 + (i & 2047);
    float s0 = 0.f, s1 = 0.f, s2 = 0.f, s3 = 0.f;
    #pragma unroll 4
    for (int j = 0; j < NBBT; j += 4) {
        s0 += p[j * 2048];       s1 += p[(j + 1) * 2048];
        s2 += p[(j + 2) * 2048]; s3 += p[(j + 3) * 2048];
    }
    const float cnt = counts[b * RS + r];
    out[i] = cnt > 0.f ? ((s0 + s1) + (s2 + s3)) / cnt : 0.f;
}

extern "C" void kernel_launch(void* const* d_in, const int* in_sizes, int n_in,
                              void* d_out, int out_size, void* d_ws, size_t ws_size,
                              hipStream_t stream) {
    const float* feat = (const float*)d_in[0];
    const int* seg = (const int*)d_in[1];
    float* out = (float*)d_out;
    float* counts = (float*)d_ws;                   // BB*RS floats
    float* part = (float*)d_ws + PART_OFF;          // 16*108*2048 floats (~14 MB)

    (void)hipMemsetAsync(d_ws, 0, (size_t)(BB * RS) * sizeof(float), stream);

    seg_hist<<<dim3((BB * NVOX) / 1024), 256, 0, stream>>>(seg, counts);
    seg_sum<<<dim3(NVOX / BLKV, TT, BB), 256, 0, stream>>>(feat, seg, part);
    seg_div<<<dim3(out_size / 64), 64, 0, stream>>>(part, counts, out);
}